// Round 2
// baseline (281.210 us; speedup 1.0000x reference)
//
#include <hip/hip_runtime.h>
#include <hip/hip_bf16.h>
#include <math.h>

#define N_NODES 100000
#define E_EDGES 1600000
#define IN_F 256
#define OUT_F 128
#define LRELU_ALPHA 0.2f

typedef __attribute__((ext_vector_type(8))) short bf16x8;
typedef __attribute__((ext_vector_type(4))) float f32x4;

__device__ __forceinline__ unsigned short f32_to_bf16(float f) {
  unsigned int u = __float_as_uint(f);
  u = (u + 0x7fffu + ((u >> 16) & 1u)) >> 16;  // round-to-nearest-even
  return (unsigned short)u;
}
// packed fp32x2 -> bf16x2 (low = a, high = b); uses v_cvt_pk_bf16_f32 on gfx950
__device__ __forceinline__ unsigned cvt2(float a, float b) {
  __hip_bfloat162 v = __float22bfloat162_rn(make_float2(a, b));
  unsigned u;
  __builtin_memcpy(&u, &v, 4);
  return u;
}
__device__ __forceinline__ float blo(unsigned u) {
  return __uint_as_float(u << 16);
}
__device__ __forceinline__ float bhi(unsigned u) {
  return __uint_as_float(u & 0xffff0000u);
}
__device__ __forceinline__ void fma8(float* acc, float a, uint4 g) {
  acc[0] = fmaf(a, blo(g.x), acc[0]);
  acc[1] = fmaf(a, bhi(g.x), acc[1]);
  acc[2] = fmaf(a, blo(g.y), acc[2]);
  acc[3] = fmaf(a, bhi(g.y), acc[3]);
  acc[4] = fmaf(a, blo(g.z), acc[4]);
  acc[5] = fmaf(a, bhi(g.z), acc[5]);
  acc[6] = fmaf(a, blo(g.w), acc[6]);
  acc[7] = fmaf(a, bhi(g.w), acc[7]);
}
__device__ __forceinline__ float elu1(float x) {
  return x > 0.f ? x : __expf(x) - 1.f;
}

// ---------------------------------------------------------------------------
// Prep: blocks [0,390]: row_ptr binary search; blocks [391,518]:
// Wt16[n][k] = bf16(W[k][n]).
// ---------------------------------------------------------------------------
#define ROWPTR_BLOCKS 391
__global__ void prep_kernel(const int* __restrict__ row,
                            int* __restrict__ row_ptr,
                            const float* __restrict__ W,
                            unsigned short* __restrict__ Wt16) {
  const int b = blockIdx.x;
  if (b < ROWPTR_BLOCKS) {
    const int i = b * 256 + threadIdx.x;
    if (i > N_NODES) return;
    int lo = 0, hi = E_EDGES;
    while (lo < hi) {
      const int mid = (lo + hi) >> 1;
      if (row[mid] < i) lo = mid + 1; else hi = mid;
    }
    row_ptr[i] = lo;
  } else {
    const int idx = (b - ROWPTR_BLOCKS) * 256 + threadIdx.x;  // 0..32767
    const int n = idx >> 8;
    const int k = idx & 255;
    Wt16[n * IN_F + k] = f32_to_bf16(W[k * OUT_F + n]);
  }
}

// ---------------------------------------------------------------------------
// Kernel 1: Wh16 = bf16(h @ W) via MFMA 16x16x32_bf16.
// R2 rewrite: B (Wt16, 64 KB) is staged into padded LDS ONCE per block
// (stride 264 ushorts = 528 B -> uniform bank spread for b128 ops), then the
// K-loop runs with ZERO barriers: A fragments stream directly from global
// (each h row is read exactly once, coalesced 16B/lane), cvt_pk to bf16 in
// registers, MFMA. No per-iteration vmcnt(0) drains; compiler pipelines the
// A loads across unrolled iterations.
// ---------------------------------------------------------------------------
#define BS_STRIDE 264   // ushorts; 528 B row stride (16B-aligned, ==16 mod 128)
#define OS_STRIDE 136
__global__ __launch_bounds__(256, 2) void gemm_mfma(
    const float* __restrict__ h, const unsigned short* __restrict__ Wt16,
    const float* __restrict__ a_src, const float* __restrict__ a_dst,
    unsigned short* __restrict__ Wh16, float* __restrict__ f1,
    float* __restrict__ f2) {
  __shared__ unsigned short Bs[128 * BS_STRIDE];  // 67584 B; reused for C-out
  __shared__ float fred[2][128][2];               // 2048 B (wc, row, f1/f2)

  const int tid = threadIdx.x;
  const int lane = tid & 63;
  const int w = tid >> 6;        // wave 0..3
  const int wr = w >> 1;         // wave row 0..1 (x64 rows)
  const int wc = w & 1;          // wave col 0..1 (x64 cols)
  const int quad = lane >> 4;    // 0..3
  const int lm = lane & 15;      // m/n within tile
  const int m0 = blockIdx.x * 128;
  const int srow = tid >> 1;     // output-copy row 0..127
  const int shalf = tid & 1;

  // ---- stage ALL of B once: Wt16[n][k] -> Bs[n*264 + k]
  {
    const int n = tid >> 1, half = tid & 1;
    const uint4* src =
        reinterpret_cast<const uint4*>(Wt16 + n * IN_F + half * 128);
#pragma unroll
    for (int i = 0; i < 16; ++i)
      *reinterpret_cast<uint4*>(&Bs[n * BS_STRIDE + half * 128 + i * 8]) =
          src[i];
  }

  f32x4 acc[4][4];
#pragma unroll
  for (int a = 0; a < 4; ++a)
#pragma unroll
    for (int b = 0; b < 4; ++b) acc[a][b] = (f32x4){0.f, 0.f, 0.f, 0.f};

  const float* hA[4];
#pragma unroll
  for (int t = 0; t < 4; ++t) {
    const int r = min(m0 + wr * 64 + t * 16 + lm, N_NODES - 1);
    hA[t] = h + (size_t)r * IN_F + quad * 8;
  }

  __syncthreads();  // B resident; no more barriers until epilogue

#pragma unroll 4
  for (int k0 = 0; k0 < IN_F; k0 += 32) {
    bf16x8 af[4], bfr[4];
#pragma unroll
    for (int t = 0; t < 4; ++t) {
      const float4 u0 = *reinterpret_cast<const float4*>(hA[t] + k0);
      const float4 u1 = *reinterpret_cast<const float4*>(hA[t] + k0 + 4);
      uint4 p;
      p.x = cvt2(u0.x, u0.y); p.y = cvt2(u0.z, u0.w);
      p.z = cvt2(u1.x, u1.y); p.w = cvt2(u1.z, u1.w);
      af[t] = *reinterpret_cast<bf16x8*>(&p);
    }
#pragma unroll
    for (int tc = 0; tc < 4; ++tc)
      bfr[tc] = *reinterpret_cast<const bf16x8*>(
          &Bs[(wc * 64 + tc * 16 + lm) * BS_STRIDE + k0 + quad * 8]);
#pragma unroll
    for (int tr = 0; tr < 4; ++tr)
#pragma unroll
      for (int tc = 0; tc < 4; ++tc)
        acc[tr][tc] = __builtin_amdgcn_mfma_f32_16x16x32_bf16(
            af[tr], bfr[tc], acc[tr][tc], 0, 0, 0);
  }

  // ---- epilogue 1: f1/f2 partials -> LDS (per-wave disjoint), no atomics
  float asv[4], adv[4];
#pragma unroll
  for (int tc = 0; tc < 4; ++tc) {
    asv[tc] = a_src[wc * 64 + tc * 16 + lm];
    adv[tc] = a_dst[wc * 64 + tc * 16 + lm];
  }
#pragma unroll
  for (int tr = 0; tr < 4; ++tr) {
#pragma unroll
    for (int reg = 0; reg < 4; ++reg) {
      float p1 = 0.f, p2 = 0.f;
#pragma unroll
      for (int tc = 0; tc < 4; ++tc) {
        p1 = fmaf(acc[tr][tc][reg], asv[tc], p1);
        p2 = fmaf(acc[tr][tc][reg], adv[tc], p2);
      }
#pragma unroll
      for (int o = 1; o < 16; o <<= 1) {  // reduce the 16 lm lanes
        p1 += __shfl_xor(p1, o);
        p2 += __shfl_xor(p2, o);
      }
      if (lm == 0) {
        const int r = wr * 64 + tr * 16 + quad * 4 + reg;
        fred[wc][r][0] = p1;
        fred[wc][r][1] = p2;
      }
    }
  }

  // ---- epilogue 2: stage C tile to LDS (reuse Bs), combine f1/f2 halves
  __syncthreads();  // K-loop Bs reads done everywhere; fred fully written
#pragma unroll
  for (int tr = 0; tr < 4; ++tr)
#pragma unroll
    for (int tc = 0; tc < 4; ++tc)
#pragma unroll
      for (int reg = 0; reg < 4; ++reg)
        Bs[(wr * 64 + tr * 16 + quad * 4 + reg) * OS_STRIDE + wc * 64 +
           tc * 16 + lm] = f32_to_bf16(acc[tr][tc][reg]);
  if (tid < 128) {
    const int grow = m0 + tid;
    if (grow < N_NODES) {
      f1[grow] = fred[0][tid][0] + fred[1][tid][0];
      f2[grow] = fred[0][tid][1] + fred[1][tid][1];
    }
  }
  __syncthreads();
  // each (srow, shalf) thread copies 64 contiguous ushorts = 8 uint4
  if (m0 + srow < N_NODES) {
    uint4* dst =
        reinterpret_cast<uint4*>(&Wh16[(m0 + srow) * OUT_F + shalf * 64]);
    const uint4* src =
        reinterpret_cast<const uint4*>(&Bs[srow * OS_STRIDE + shalf * 64]);
#pragma unroll
    for (int i = 0; i < 8; ++i) dst[i] = src[i];
  }
}

// ---------------------------------------------------------------------------
// Kernel 2: segment softmax + SpMM + ELU. One wave per node, 4 nodes/block.
// v6: gather granularity fixed. Lane = (sub = lane>>4, fl = lane&15); each
// lane gathers uint4 (8 bf16 features), 16 lanes cover one 256 B Wh row, so
// a wave handles 4 edges per load instruction. Per 8 edges: 2 ds_read_b64 +
// 2 global_load_dwordx4 + 2 addr adds (was 8+8+8). FMA count unchanged
// (8 acc/lane). shfl_xor(^16,^32) butterfly merges the 4 sub-partials; subs
// 0/1 store float4s (full 512 B row, coalesced).
// ---------------------------------------------------------------------------
__global__ __launch_bounds__(256) void gat_v6(
    const uint4* __restrict__ Whq,  // Wh16 viewed as uint4 [N][16]
    const float* __restrict__ f1, const float* __restrict__ f2,
    const int* __restrict__ row_ptr, const int* __restrict__ col,
    float* __restrict__ out) {
  __shared__ int2 edge_s[4][128];

  const int w = threadIdx.x >> 6;
  const int lane = threadIdx.x & 63;
  const int sub = lane >> 4;   // edge slot 0..3
  const int fl = lane & 15;    // feature block (8 bf16 = 16 B)
  const int node = blockIdx.x * 4 + w;

  const int start = row_ptr[node];
  const int deg = row_ptr[node + 1] - start;
  float4* outp =
      reinterpret_cast<float4*>(&out[node * OUT_F + fl * 8 + sub * 4]);

  if (deg == 0) {
    if (sub < 2) *outp = make_float4(0.f, 0.f, 0.f, 0.f);
    return;
  }
  const float f1i = f1[node];
  float acc[8] = {0.f, 0.f, 0.f, 0.f, 0.f, 0.f, 0.f, 0.f};
  float s = 0.f, inv;

  if (deg <= 128) {
    // fused pass: logits -> exp -> LDS, running sum (no max subtraction:
    // logits are ~N(0,1.6^2), fp32-safe, exact-math identical to reference)
    for (int idx = lane; idx < deg; idx += 64) {
      const int c = col[start + idx];
      float v = f1i + f2[c];
      v = fmaxf(v, LRELU_ALPHA * v);  // leaky-relu, alpha < 1
      const float x = __expf(v);
      edge_s[w][idx] = make_int2(__float_as_int(x), c << 4);  // c*16 uint4 idx
      s += x;
    }
#pragma unroll
    for (int o = 32; o > 0; o >>= 1) s += __shfl_xor(s, o);
    inv = 1.f / s;
    __builtin_amdgcn_wave_barrier();
    // pad to multiple of 8 with zero-contribution entries (att=0, col=0)
    const int padded = (deg + 7) & ~7;
    if (lane < padded - deg)
      edge_s[w][deg + lane] = make_int2(0, 0);  // 0.0f bits, row 0 (L2-hot)
    __builtin_amdgcn_wave_barrier();
    // pass C: guard-free, 8 edges / iter, 2 wide gathers + 2 ds reads
    for (int j = 0; j < padded; j += 8) {
      const int2 e0 = edge_s[w][j + sub];
      const int2 e1 = edge_s[w][j + 4 + sub];
      const uint4 g0 = Whq[e0.y + fl];
      const uint4 g1 = Whq[e1.y + fl];
      fma8(acc, __int_as_float(e0.x), g0);
      fma8(acc, __int_as_float(e1.x), g1);
    }
  } else {
    // slow path (deg > 128, ~never at mean degree 16): 3-pass recompute,
    // keeps max-subtraction for safety.
    float m = -INFINITY;
    for (int idx = lane; idx < deg; idx += 64) {
      float v = f1i + f2[col[start + idx]];
      v = fmaxf(v, LRELU_ALPHA * v);
      m = fmaxf(m, v);
    }
#pragma unroll
    for (int o = 32; o > 0; o >>= 1) m = fmaxf(m, __shfl_xor(m, o));
    for (int idx = lane; idx < deg; idx += 64) {
      float v = f1i + f2[col[start + idx]];
      v = fmaxf(v, LRELU_ALPHA * v);
      s += __expf(v - m);
    }
#pragma unroll
    for (int o = 32; o > 0; o >>= 1) s += __shfl_xor(s, o);
    inv = 1.f / s;
    for (int j = 0; j < deg; j += 4) {
      const int e = j + sub;
      const bool ok = e < deg;
      const int c = ok ? col[start + e] : 0;
      float v = f1i + f2[c];
      v = fmaxf(v, LRELU_ALPHA * v);
      const float a = ok ? __expf(v - m) : 0.f;
      const uint4 g = Whq[c * 16 + fl];
      fma8(acc, a, g);
    }
  }

  // merge the 4 edge-subgroup partials (subs differ; fl groups independent)
#pragma unroll
  for (int i = 0; i < 8; ++i) {
    acc[i] += __shfl_xor(acc[i], 16);
    acc[i] += __shfl_xor(acc[i], 32);
  }
  if (sub < 2) {
    float4 r;
    r.x = elu1(((sub == 0) ? acc[0] : acc[4]) * inv);
    r.y = elu1(((sub == 0) ? acc[1] : acc[5]) * inv);
    r.z = elu1(((sub == 0) ? acc[2] : acc[6]) * inv);
    r.w = elu1(((sub == 0) ? acc[3] : acc[7]) * inv);
    *outp = r;
  }
}

// ---------------------------------------------------------------------------
extern "C" void kernel_launch(void* const* d_in, const int* in_sizes, int n_in,
                              void* d_out, int out_size, void* d_ws,
                              size_t ws_size, hipStream_t stream) {
  const float* h     = (const float*)d_in[0];
  const float* W     = (const float*)d_in[1];
  const float* a_src = (const float*)d_in[2];
  const float* a_dst = (const float*)d_in[3];
  const int*   row   = (const int*)d_in[4];
  const int*   col   = (const int*)d_in[5];
  float* out = (float*)d_out;

  char* ws = (char*)d_ws;
  unsigned short* Wh16 = (unsigned short*)(ws);        // N*128*2 = 25,600,000 B
  float* f1      = (float*)(ws + 25600000);            //    400,000 B
  float* f2      = (float*)(ws + 26000000);            //    400,000 B
  int*   row_ptr = (int*)  (ws + 26400000);            //    400,004 B
  unsigned short* Wt16 = (unsigned short*)(ws + 26800016);  // 64 KB, align16

  hipLaunchKernelGGL(prep_kernel, dim3(ROWPTR_BLOCKS + 128), dim3(256), 0,
                     stream, row, row_ptr, W, Wt16);
  hipLaunchKernelGGL(gemm_mfma, dim3((N_NODES + 127) / 128), dim3(256), 0,
                     stream, h, Wt16, a_src, a_dst, Wh16, f1, f2);
  hipLaunchKernelGGL(gat_v6, dim3(N_NODES / 4), dim3(256), 0, stream,
                     (const uint4*)Wh16, f1, f2, row_ptr, col, out);
}

// Round 3
// 272.669 us; speedup vs baseline: 1.0313x; 1.0313x over previous
//
#include <hip/hip_runtime.h>
#include <hip/hip_bf16.h>
#include <math.h>

#define N_NODES 100000
#define E_EDGES 1600000
#define IN_F 256
#define OUT_F 128
#define LRELU_ALPHA 0.2f

typedef __attribute__((ext_vector_type(8))) short bf16x8;
typedef __attribute__((ext_vector_type(4))) float f32x4;

__device__ __forceinline__ unsigned short f32_to_bf16(float f) {
  unsigned int u = __float_as_uint(f);
  u = (u + 0x7fffu + ((u >> 16) & 1u)) >> 16;  // round-to-nearest-even
  return (unsigned short)u;
}
// packed fp32x2 -> bf16x2 (low = a, high = b); uses v_cvt_pk_bf16_f32 on gfx950
__device__ __forceinline__ unsigned cvt2(float a, float b) {
  __hip_bfloat162 v = __float22bfloat162_rn(make_float2(a, b));
  unsigned u;
  __builtin_memcpy(&u, &v, 4);
  return u;
}
__device__ __forceinline__ float blo(unsigned u) {
  return __uint_as_float(u << 16);
}
__device__ __forceinline__ float bhi(unsigned u) {
  return __uint_as_float(u & 0xffff0000u);
}
__device__ __forceinline__ void fma8(float* acc, float a, uint4 g) {
  acc[0] = fmaf(a, blo(g.x), acc[0]);
  acc[1] = fmaf(a, bhi(g.x), acc[1]);
  acc[2] = fmaf(a, blo(g.y), acc[2]);
  acc[3] = fmaf(a, bhi(g.y), acc[3]);
  acc[4] = fmaf(a, blo(g.z), acc[4]);
  acc[5] = fmaf(a, bhi(g.z), acc[5]);
  acc[6] = fmaf(a, blo(g.w), acc[6]);
  acc[7] = fmaf(a, bhi(g.w), acc[7]);
}
__device__ __forceinline__ float elu1(float x) {
  return x > 0.f ? x : __expf(x) - 1.f;
}

// ---------------------------------------------------------------------------
// Prep: blocks [0,390]: row_ptr binary search; blocks [391,518]:
// Wt16[n][k] = bf16(W[k][n]).
// ---------------------------------------------------------------------------
#define ROWPTR_BLOCKS 391
__global__ void prep_kernel(const int* __restrict__ row,
                            int* __restrict__ row_ptr,
                            const float* __restrict__ W,
                            unsigned short* __restrict__ Wt16) {
  const int b = blockIdx.x;
  if (b < ROWPTR_BLOCKS) {
    const int i = b * 256 + threadIdx.x;
    if (i > N_NODES) return;
    int lo = 0, hi = E_EDGES;
    while (lo < hi) {
      const int mid = (lo + hi) >> 1;
      if (row[mid] < i) lo = mid + 1; else hi = mid;
    }
    row_ptr[i] = lo;
  } else {
    const int idx = (b - ROWPTR_BLOCKS) * 256 + threadIdx.x;  // 0..32767
    const int n = idx >> 8;
    const int k = idx & 255;
    Wt16[n * IN_F + k] = f32_to_bf16(W[k * OUT_F + n]);
  }
}

// ---------------------------------------------------------------------------
// Kernel 1: Wh16 = bf16(h @ W) via MFMA 16x16x32_bf16.
// R3: revert to the R1 high-occupancy structure (per-K-step LDS staging,
// prefetch issued AFTER the second barrier so it flies during ds_read+MFMA),
// with BK widened 32 -> 64: halves the per-block barrier/vmcnt(0)-drain count
// from 16 to 8. LDS = 2*128*72*2 + 2048 = 38.9 KB -> 4 blocks/CU.
// Fragment-read bank spread at 144 B row stride: group = 4*(lm+quad) mod 32,
// uniform over all 8 four-bank groups (b128 minimum, conflict-free).
// ---------------------------------------------------------------------------
#define AS_STRIDE 72    // 64 k-values + 8 pad (ushorts); 144 B row stride
#define OS_STRIDE 136
__global__ __launch_bounds__(256) void gemm_mfma(
    const float* __restrict__ h, const unsigned short* __restrict__ Wt16,
    const float* __restrict__ a_src, const float* __restrict__ a_dst,
    unsigned short* __restrict__ Wh16, float* __restrict__ f1,
    float* __restrict__ f2) {
  __shared__ unsigned short lds[2 * 128 * AS_STRIDE];  // 36864 B
  __shared__ float fred[2][128][2];                    // 2048 B
  unsigned short* As = lds;                            // [128][72]
  unsigned short* Bs = lds + 128 * AS_STRIDE;          // [128][72]

  const int tid = threadIdx.x;
  const int lane = tid & 63;
  const int w = tid >> 6;        // wave 0..3
  const int wr = w >> 1;         // wave row 0..1 (x64 rows)
  const int wc = w & 1;          // wave col 0..1 (x64 cols)
  const int quad = lane >> 4;    // 0..3
  const int lm = lane & 15;      // m/n within tile
  const int m0 = blockIdx.x * 128;

  const int srow = tid >> 1;     // staging row 0..127
  const int shalf = tid & 1;     // staging k-half (32 elements)

  f32x4 acc[4][4];
#pragma unroll
  for (int a = 0; a < 4; ++a)
#pragma unroll
    for (int b = 0; b < 4; ++b) acc[a][b] = (f32x4){0.f, 0.f, 0.f, 0.f};

  const int gr = min(m0 + srow, N_NODES - 1);  // clamp tail-block loads
  const float* hrow = &h[(size_t)gr * IN_F + shalf * 32];
  const unsigned short* wrow = &Wt16[srow * IN_F + shalf * 32];

  // prologue: issue k0 = 0 tile loads (32 k-values per thread)
  float4 ha[8];
  uint4 wa[4];
  {
    const float4* hp = reinterpret_cast<const float4*>(hrow);
#pragma unroll
    for (int i = 0; i < 8; ++i) ha[i] = hp[i];
    const uint4* wp = reinterpret_cast<const uint4*>(wrow);
#pragma unroll
    for (int i = 0; i < 4; ++i) wa[i] = wp[i];
  }

  for (int k0 = 0; k0 < IN_F; k0 += 64) {
    __syncthreads();  // previous tile's LDS reads complete
    {
      uint4* as = reinterpret_cast<uint4*>(&As[srow * AS_STRIDE + shalf * 32]);
      uint4* bs = reinterpret_cast<uint4*>(&Bs[srow * AS_STRIDE + shalf * 32]);
#pragma unroll
      for (int j = 0; j < 4; ++j) {
        uint4 p;
        p.x = cvt2(ha[2 * j].x, ha[2 * j].y);
        p.y = cvt2(ha[2 * j].z, ha[2 * j].w);
        p.z = cvt2(ha[2 * j + 1].x, ha[2 * j + 1].y);
        p.w = cvt2(ha[2 * j + 1].z, ha[2 * j + 1].w);
        as[j] = p;
        bs[j] = wa[j];
      }
    }
    __syncthreads();

    // issue NEXT tile's global loads: latency covered by ds_read + MFMA below
    if (k0 + 64 < IN_F) {
      const float4* hp = reinterpret_cast<const float4*>(hrow + k0 + 64);
#pragma unroll
      for (int i = 0; i < 8; ++i) ha[i] = hp[i];
      const uint4* wp = reinterpret_cast<const uint4*>(wrow + k0 + 64);
#pragma unroll
      for (int i = 0; i < 4; ++i) wa[i] = wp[i];
    }

#pragma unroll
    for (int ks = 0; ks < 2; ++ks) {
      bf16x8 af[4], bfr[4];
#pragma unroll
      for (int t = 0; t < 4; ++t) {
        af[t] = *reinterpret_cast<const bf16x8*>(
            &As[(wr * 64 + t * 16 + lm) * AS_STRIDE + ks * 32 + quad * 8]);
        bfr[t] = *reinterpret_cast<const bf16x8*>(
            &Bs[(wc * 64 + t * 16 + lm) * AS_STRIDE + ks * 32 + quad * 8]);
      }
#pragma unroll
      for (int tr = 0; tr < 4; ++tr)
#pragma unroll
        for (int tc = 0; tc < 4; ++tc)
          acc[tr][tc] = __builtin_amdgcn_mfma_f32_16x16x32_bf16(
              af[tr], bfr[tc], acc[tr][tc], 0, 0, 0);
    }
  }

  // ---- epilogue 1: f1/f2 partials -> LDS (per-wave disjoint), no atomics
  float asv[4], adv[4];
#pragma unroll
  for (int tc = 0; tc < 4; ++tc) {
    asv[tc] = a_src[wc * 64 + tc * 16 + lm];
    adv[tc] = a_dst[wc * 64 + tc * 16 + lm];
  }
#pragma unroll
  for (int tr = 0; tr < 4; ++tr) {
#pragma unroll
    for (int reg = 0; reg < 4; ++reg) {
      float p1 = 0.f, p2 = 0.f;
#pragma unroll
      for (int tc = 0; tc < 4; ++tc) {
        p1 = fmaf(acc[tr][tc][reg], asv[tc], p1);
        p2 = fmaf(acc[tr][tc][reg], adv[tc], p2);
      }
#pragma unroll
      for (int o = 1; o < 16; o <<= 1) {  // reduce the 16 lm lanes
        p1 += __shfl_xor(p1, o);
        p2 += __shfl_xor(p2, o);
      }
      if (lm == 0) {
        const int r = wr * 64 + tr * 16 + quad * 4 + reg;
        fred[wc][r][0] = p1;
        fred[wc][r][1] = p2;
      }
    }
  }

  // ---- epilogue 2: stage C tile to LDS (reuse As/Bs), combine f1/f2 halves
  __syncthreads();  // K-loop LDS reads done everywhere; fred fully written
#pragma unroll
  for (int tr = 0; tr < 4; ++tr)
#pragma unroll
    for (int tc = 0; tc < 4; ++tc)
#pragma unroll
      for (int reg = 0; reg < 4; ++reg)
        lds[(wr * 64 + tr * 16 + quad * 4 + reg) * OS_STRIDE + wc * 64 +
            tc * 16 + lm] = f32_to_bf16(acc[tr][tc][reg]);
  if (tid < 128) {
    const int grow = m0 + tid;
    if (grow < N_NODES) {
      f1[grow] = fred[0][tid][0] + fred[1][tid][0];
      f2[grow] = fred[0][tid][1] + fred[1][tid][1];
    }
  }
  __syncthreads();
  // each (srow, shalf) thread copies 64 contiguous ushorts = 4 uint4
  if (m0 + srow < N_NODES) {
    uint4* dst =
        reinterpret_cast<uint4*>(&Wh16[(m0 + srow) * OUT_F + shalf * 64]);
    const uint4* src =
        reinterpret_cast<const uint4*>(&lds[srow * OS_STRIDE + shalf * 64]);
#pragma unroll
    for (int i = 0; i < 8; ++i) dst[i] = src[i];
  }
}

// ---------------------------------------------------------------------------
// Kernel 2: segment softmax + SpMM + ELU. One wave per node, 4 nodes/block.
// v6 (unchanged from R2 for a clean A/B read): wide gathers — lane =
// (sub = lane>>4, fl = lane&15); each lane gathers uint4 (8 bf16), 16 lanes
// cover one 256 B Wh row, 4 edges per load instruction.
// ---------------------------------------------------------------------------
__global__ __launch_bounds__(256) void gat_v6(
    const uint4* __restrict__ Whq,  // Wh16 viewed as uint4 [N][16]
    const float* __restrict__ f1, const float* __restrict__ f2,
    const int* __restrict__ row_ptr, const int* __restrict__ col,
    float* __restrict__ out) {
  __shared__ int2 edge_s[4][128];

  const int w = threadIdx.x >> 6;
  const int lane = threadIdx.x & 63;
  const int sub = lane >> 4;   // edge slot 0..3
  const int fl = lane & 15;    // feature block (8 bf16 = 16 B)
  const int node = blockIdx.x * 4 + w;

  const int start = row_ptr[node];
  const int deg = row_ptr[node + 1] - start;
  float4* outp =
      reinterpret_cast<float4*>(&out[node * OUT_F + fl * 8 + sub * 4]);

  if (deg == 0) {
    if (sub < 2) *outp = make_float4(0.f, 0.f, 0.f, 0.f);
    return;
  }
  const float f1i = f1[node];
  float acc[8] = {0.f, 0.f, 0.f, 0.f, 0.f, 0.f, 0.f, 0.f};
  float s = 0.f, inv;

  if (deg <= 128) {
    // fused pass: logits -> exp -> LDS, running sum (no max subtraction:
    // logits are ~N(0,1.6^2), fp32-safe, exact-math identical to reference)
    for (int idx = lane; idx < deg; idx += 64) {
      const int c = col[start + idx];
      float v = f1i + f2[c];
      v = fmaxf(v, LRELU_ALPHA * v);  // leaky-relu, alpha < 1
      const float x = __expf(v);
      edge_s[w][idx] = make_int2(__float_as_int(x), c << 4);  // c*16 uint4 idx
      s += x;
    }
#pragma unroll
    for (int o = 32; o > 0; o >>= 1) s += __shfl_xor(s, o);
    inv = 1.f / s;
    __builtin_amdgcn_wave_barrier();
    // pad to multiple of 8 with zero-contribution entries (att=0, col=0)
    const int padded = (deg + 7) & ~7;
    if (lane < padded - deg)
      edge_s[w][deg + lane] = make_int2(0, 0);  // 0.0f bits, row 0 (L2-hot)
    __builtin_amdgcn_wave_barrier();
    // pass C: guard-free, 8 edges / iter, 2 wide gathers + 2 ds reads
    for (int j = 0; j < padded; j += 8) {
      const int2 e0 = edge_s[w][j + sub];
      const int2 e1 = edge_s[w][j + 4 + sub];
      const uint4 g0 = Whq[e0.y + fl];
      const uint4 g1 = Whq[e1.y + fl];
      fma8(acc, __int_as_float(e0.x), g0);
      fma8(acc, __int_as_float(e1.x), g1);
    }
  } else {
    // slow path (deg > 128, ~never at mean degree 16): 3-pass recompute,
    // keeps max-subtraction for safety.
    float m = -INFINITY;
    for (int idx = lane; idx < deg; idx += 64) {
      float v = f1i + f2[col[start + idx]];
      v = fmaxf(v, LRELU_ALPHA * v);
      m = fmaxf(m, v);
    }
#pragma unroll
    for (int o = 32; o > 0; o >>= 1) m = fmaxf(m, __shfl_xor(m, o));
    for (int idx = lane; idx < deg; idx += 64) {
      float v = f1i + f2[col[start + idx]];
      v = fmaxf(v, LRELU_ALPHA * v);
      s += __expf(v - m);
    }
#pragma unroll
    for (int o = 32; o > 0; o >>= 1) s += __shfl_xor(s, o);
    inv = 1.f / s;
    for (int j = 0; j < deg; j += 4) {
      const int e = j + sub;
      const bool ok = e < deg;
      const int c = ok ? col[start + e] : 0;
      float v = f1i + f2[c];
      v = fmaxf(v, LRELU_ALPHA * v);
      const float a = ok ? __expf(v - m) : 0.f;
      const uint4 g = Whq[c * 16 + fl];
      fma8(acc, a, g);
    }
  }

  // merge the 4 edge-subgroup partials (subs differ; fl groups independent)
#pragma unroll
  for (int i = 0; i < 8; ++i) {
    acc[i] += __shfl_xor(acc[i], 16);
    acc[i] += __shfl_xor(acc[i], 32);
  }
  if (sub < 2) {
    float4 r;
    r.x = elu1(((sub == 0) ? acc[0] : acc[4]) * inv);
    r.y = elu1(((sub == 0) ? acc[1] : acc[5]) * inv);
    r.z = elu1(((sub == 0) ? acc[2] : acc[6]) * inv);
    r.w = elu1(((sub == 0) ? acc[3] : acc[7]) * inv);
    *outp = r;
  }
}

// ---------------------------------------------------------------------------
extern "C" void kernel_launch(void* const* d_in, const int* in_sizes, int n_in,
                              void* d_out, int out_size, void* d_ws,
                              size_t ws_size, hipStream_t stream) {
  const float* h     = (const float*)d_in[0];
  const float* W     = (const float*)d_in[1];
  const float* a_src = (const float*)d_in[2];
  const float* a_dst = (const float*)d_in[3];
  const int*   row   = (const int*)d_in[4];
  const int*   col   = (const int*)d_in[5];
  float* out = (float*)d_out;

  char* ws = (char*)d_ws;
  unsigned short* Wh16 = (unsigned short*)(ws);        // N*128*2 = 25,600,000 B
  float* f1      = (float*)(ws + 25600000);            //    400,000 B
  float* f2      = (float*)(ws + 26000000);            //    400,000 B
  int*   row_ptr = (int*)  (ws + 26400000);            //    400,004 B
  unsigned short* Wt16 = (unsigned short*)(ws + 26800016);  // 64 KB, align16

  hipLaunchKernelGGL(prep_kernel, dim3(ROWPTR_BLOCKS + 128), dim3(256), 0,
                     stream, row, row_ptr, W, Wt16);
  hipLaunchKernelGGL(gemm_mfma, dim3((N_NODES + 127) / 128), dim3(256), 0,
                     stream, h, Wt16, a_src, a_dst, Wh16, f1, f2);
  hipLaunchKernelGGL(gat_v6, dim3(N_NODES / 4), dim3(256), 0, stream,
                     (const uint4*)Wh16, f1, f2, row_ptr, col, out);
}

// Round 4
// 257.591 us; speedup vs baseline: 1.0917x; 1.0585x over previous
//
#include <hip/hip_runtime.h>
#include <hip/hip_bf16.h>
#include <math.h>

#define N_NODES 100000
#define E_EDGES 1600000
#define IN_F 256
#define OUT_F 128
#define LRELU_ALPHA 0.2f

typedef __attribute__((ext_vector_type(8))) short bf16x8;
typedef __attribute__((ext_vector_type(4))) float f32x4;

__device__ __forceinline__ unsigned short f32_to_bf16(float f) {
  unsigned int u = __float_as_uint(f);
  u = (u + 0x7fffu + ((u >> 16) & 1u)) >> 16;  // round-to-nearest-even
  return (unsigned short)u;
}
// packed fp32x2 -> bf16x2 (low = a, high = b); uses v_cvt_pk_bf16_f32 on gfx950
__device__ __forceinline__ unsigned cvt2(float a, float b) {
  __hip_bfloat162 v = __float22bfloat162_rn(make_float2(a, b));
  unsigned u;
  __builtin_memcpy(&u, &v, 4);
  return u;
}
__device__ __forceinline__ float blo(unsigned u) {
  return __uint_as_float(u << 16);
}
__device__ __forceinline__ float bhi(unsigned u) {
  return __uint_as_float(u & 0xffff0000u);
}
__device__ __forceinline__ void fma8(float* acc, float a, uint4 g) {
  acc[0] = fmaf(a, blo(g.x), acc[0]);
  acc[1] = fmaf(a, bhi(g.x), acc[1]);
  acc[2] = fmaf(a, blo(g.y), acc[2]);
  acc[3] = fmaf(a, bhi(g.y), acc[3]);
  acc[4] = fmaf(a, blo(g.z), acc[4]);
  acc[5] = fmaf(a, bhi(g.z), acc[5]);
  acc[6] = fmaf(a, blo(g.w), acc[6]);
  acc[7] = fmaf(a, bhi(g.w), acc[7]);
}
__device__ __forceinline__ float elu1(float x) {
  return x > 0.f ? x : __expf(x) - 1.f;
}

// fire-and-forget global -> LDS, 16 B per lane (dest = uniform base + lane*16)
typedef __attribute__((address_space(1))) const unsigned int gu32;
typedef __attribute__((address_space(3))) unsigned int lu32;
__device__ __forceinline__ void gll16(const void* g, void* l) {
  __builtin_amdgcn_global_load_lds((gu32*)g, (lu32*)l, 16, 0, 0);
}

// ---------------------------------------------------------------------------
// Prep: blocks [0,390]: row_ptr binary search; blocks [391,518]:
// Wt16[n][k] = bf16(W[k][n]).
// ---------------------------------------------------------------------------
#define ROWPTR_BLOCKS 391
__global__ void prep_kernel(const int* __restrict__ row,
                            int* __restrict__ row_ptr,
                            const float* __restrict__ W,
                            unsigned short* __restrict__ Wt16) {
  const int b = blockIdx.x;
  if (b < ROWPTR_BLOCKS) {
    const int i = b * 256 + threadIdx.x;
    if (i > N_NODES) return;
    int lo = 0, hi = E_EDGES;
    while (lo < hi) {
      const int mid = (lo + hi) >> 1;
      if (row[mid] < i) lo = mid + 1; else hi = mid;
    }
    row_ptr[i] = lo;
  } else {
    const int idx = (b - ROWPTR_BLOCKS) * 256 + threadIdx.x;  // 0..32767
    const int n = idx >> 8;
    const int k = idx & 255;
    Wt16[n * IN_F + k] = f32_to_bf16(W[k * OUT_F + n]);
  }
}

// ---------------------------------------------------------------------------
// Kernel 1: Wh16 = bf16(h @ W) via MFMA 16x16x32_bf16.
// R4 rewrite (latency-bound fix, R3 post-mortem): tile 64x128 -> 1563 blocks
// (6.1/CU); staging via global_load_lds width-16 (fire-and-forget, no VGPR
// round-trip, no ds_writes in the K-loop); A staged raw f32 + cvt_pk at
// fragment-read (bit-identical numerics); linear unpadded LDS (gll rule);
// double-buffered, ONE barrier/iter so the vmcnt drain window = full body.
// LDS = 32768 B exactly -> 5 blocks/CU, 20 waves/CU.
// ---------------------------------------------------------------------------
#define OS_STRIDE 136
__global__ __launch_bounds__(256) void gemm_mfma(
    const float* __restrict__ h, const unsigned short* __restrict__ Wt16,
    const float* __restrict__ a_src, const float* __restrict__ a_dst,
    unsigned short* __restrict__ Wh16, float* __restrict__ f1,
    float* __restrict__ f2) {
  // buf p (p=0,1) at byte p*16384: A f32 [64 rows][32 k] = 8192 B,
  //                                B bf16 [128 n ][32 k] = 8192 B.
  // epilogue reuse: cstage ushort[64][136] = 17408 B at 0; fred at 17408.
  __shared__ unsigned short lds_us[16384];  // 32768 B
  char* ldsb = (char*)lds_us;

  const int tid = threadIdx.x;
  const int lane = tid & 63;
  const int w = tid >> 6;        // wave 0..3
  const int wr = w >> 1;         // wave row 0..1 (x32 rows)
  const int wc = w & 1;          // wave col 0..1 (x64 cols)
  const int quad = lane >> 4;    // 0..3
  const int lm = lane & 15;      // m/n within tile
  const int m0 = blockIdx.x * 64;

  f32x4 acc[2][4];
#pragma unroll
  for (int a = 0; a < 2; ++a)
#pragma unroll
    for (int b = 0; b < 4; ++b) acc[a][b] = (f32x4){0.f, 0.f, 0.f, 0.f};

  // ---- staging lambda: tile k0 into buffer p (4 gll per wave) ----
  // A: instr i covers rows 8(w+4i)..+8 (row = 128 B); lane l -> row +l/8,
  //    slot l&7 (16 B of f32).  B: rows 16(w+4i)..+16 (row = 64 B); lane l
  //    -> row +l/4, slot l&3.
  auto stage = [&](int p, int k0) {
    char* Ab = ldsb + p * 16384;
    char* Bb = Ab + 8192;
#pragma unroll
    for (int i = 0; i < 2; ++i) {
      const int r = 8 * (w + 4 * i) + (lane >> 3);
      const int gr = min(m0 + r, N_NODES - 1);  // tail clamp
      const float* src = h + (size_t)gr * IN_F + k0 + ((lane & 7) << 2);
      gll16(src, Ab + (w + 4 * i) * 1024);
    }
#pragma unroll
    for (int i = 0; i < 2; ++i) {
      const int n = 16 * (w + 4 * i) + (lane >> 2);
      const unsigned short* src = Wt16 + n * IN_F + k0 + ((lane & 3) << 3);
      gll16(src, Bb + (w + 4 * i) * 1024);
    }
  };

  stage(0, 0);  // prologue
  int p = 0;
  for (int kt = 0; kt < 8; ++kt) {
    __syncthreads();  // drains this wave's glls for buf[p]; publishes buf[p]
    if (kt < 7) stage(p ^ 1, (kt + 1) * 32);  // fire-and-forget next tile

    const float* Af = (const float*)(ldsb + p * 16384);
    const unsigned short* Bf =
        (const unsigned short*)(ldsb + p * 16384 + 8192);
    bf16x8 af[2], bfr[4];
#pragma unroll
    for (int t = 0; t < 2; ++t) {
      const int r = wr * 32 + t * 16 + lm;
      const float4 u0 = *reinterpret_cast<const float4*>(Af + r * 32 + quad * 8);
      const float4 u1 =
          *reinterpret_cast<const float4*>(Af + r * 32 + quad * 8 + 4);
      uint4 pk;
      pk.x = cvt2(u0.x, u0.y); pk.y = cvt2(u0.z, u0.w);
      pk.z = cvt2(u1.x, u1.y); pk.w = cvt2(u1.z, u1.w);
      af[t] = *reinterpret_cast<bf16x8*>(&pk);
    }
#pragma unroll
    for (int tc = 0; tc < 4; ++tc) {
      const int n = wc * 64 + tc * 16 + lm;
      bfr[tc] = *reinterpret_cast<const bf16x8*>(Bf + n * 32 + quad * 8);
    }
#pragma unroll
    for (int tr = 0; tr < 2; ++tr)
#pragma unroll
      for (int tc = 0; tc < 4; ++tc)
        acc[tr][tc] = __builtin_amdgcn_mfma_f32_16x16x32_bf16(
            af[tr], bfr[tc], acc[tr][tc], 0, 0, 0);
    p ^= 1;
  }
  __syncthreads();  // all buf reads done; LDS free for epilogue reuse

  // ---- epilogue 1: f1/f2 partials (per-wave disjoint rows), no atomics
  float* fredp = (float*)(ldsb + 17408);  // [wc][64 rows][2] = 256 floats
  float asv[4], adv[4];
#pragma unroll
  for (int tc = 0; tc < 4; ++tc) {
    asv[tc] = a_src[wc * 64 + tc * 16 + lm];
    adv[tc] = a_dst[wc * 64 + tc * 16 + lm];
  }
#pragma unroll
  for (int tr = 0; tr < 2; ++tr) {
#pragma unroll
    for (int reg = 0; reg < 4; ++reg) {
      float p1 = 0.f, p2 = 0.f;
#pragma unroll
      for (int tc = 0; tc < 4; ++tc) {
        p1 = fmaf(acc[tr][tc][reg], asv[tc], p1);
        p2 = fmaf(acc[tr][tc][reg], adv[tc], p2);
      }
#pragma unroll
      for (int o = 1; o < 16; o <<= 1) {  // reduce the 16 lm lanes
        p1 += __shfl_xor(p1, o);
        p2 += __shfl_xor(p2, o);
      }
      if (lm == 0) {
        const int r = wr * 32 + tr * 16 + quad * 4 + reg;  // 0..63
        fredp[wc * 128 + r * 2 + 0] = p1;
        fredp[wc * 128 + r * 2 + 1] = p2;
      }
    }
  }

  // ---- epilogue 2: stage C tile (bf16) to LDS, combine f1/f2 halves
#pragma unroll
  for (int tr = 0; tr < 2; ++tr)
#pragma unroll
    for (int tc = 0; tc < 4; ++tc)
#pragma unroll
      for (int reg = 0; reg < 4; ++reg)
        lds_us[(wr * 32 + tr * 16 + quad * 4 + reg) * OS_STRIDE + wc * 64 +
               tc * 16 + lm] = f32_to_bf16(acc[tr][tc][reg]);
  __syncthreads();
  if (tid < 64 && m0 + tid < N_NODES) {
    f1[m0 + tid] = fredp[tid * 2 + 0] + fredp[128 + tid * 2 + 0];
    f2[m0 + tid] = fredp[tid * 2 + 1] + fredp[128 + tid * 2 + 1];
  }
  // copy-out: thread t -> row t/4 (0..63), quarter t&3 (64 B = 4 uint4)
  {
    const int rr = tid >> 2, part = tid & 3;
    if (m0 + rr < N_NODES) {
      uint4* dst =
          reinterpret_cast<uint4*>(&Wh16[(m0 + rr) * OUT_F + part * 32]);
      const uint4* src =
          reinterpret_cast<const uint4*>(&lds_us[rr * OS_STRIDE + part * 32]);
#pragma unroll
      for (int i = 0; i < 4; ++i) dst[i] = src[i];
    }
  }
}

// ---------------------------------------------------------------------------
// Kernel 2: segment softmax + SpMM + ELU. One wave per node, 4 nodes/block.
// v6 (unchanged for a clean A/B read on gemm): wide gathers — lane =
// (sub = lane>>4, fl = lane&15); each lane gathers uint4 (8 bf16), 16 lanes
// cover one 256 B Wh row, 4 edges per load instruction.
// ---------------------------------------------------------------------------
__global__ __launch_bounds__(256) void gat_v6(
    const uint4* __restrict__ Whq,  // Wh16 viewed as uint4 [N][16]
    const float* __restrict__ f1, const float* __restrict__ f2,
    const int* __restrict__ row_ptr, const int* __restrict__ col,
    float* __restrict__ out) {
  __shared__ int2 edge_s[4][128];

  const int w = threadIdx.x >> 6;
  const int lane = threadIdx.x & 63;
  const int sub = lane >> 4;   // edge slot 0..3
  const int fl = lane & 15;    // feature block (8 bf16 = 16 B)
  const int node = blockIdx.x * 4 + w;

  const int start = row_ptr[node];
  const int deg = row_ptr[node + 1] - start;
  float4* outp =
      reinterpret_cast<float4*>(&out[node * OUT_F + fl * 8 + sub * 4]);

  if (deg == 0) {
    if (sub < 2) *outp = make_float4(0.f, 0.f, 0.f, 0.f);
    return;
  }
  const float f1i = f1[node];
  float acc[8] = {0.f, 0.f, 0.f, 0.f, 0.f, 0.f, 0.f, 0.f};
  float s = 0.f, inv;

  if (deg <= 128) {
    // fused pass: logits -> exp -> LDS, running sum (no max subtraction:
    // logits are ~N(0,1.6^2), fp32-safe, exact-math identical to reference)
    for (int idx = lane; idx < deg; idx += 64) {
      const int c = col[start + idx];
      float v = f1i + f2[c];
      v = fmaxf(v, LRELU_ALPHA * v);  // leaky-relu, alpha < 1
      const float x = __expf(v);
      edge_s[w][idx] = make_int2(__float_as_int(x), c << 4);  // c*16 uint4 idx
      s += x;
    }
#pragma unroll
    for (int o = 32; o > 0; o >>= 1) s += __shfl_xor(s, o);
    inv = 1.f / s;
    __builtin_amdgcn_wave_barrier();
    // pad to multiple of 8 with zero-contribution entries (att=0, col=0)
    const int padded = (deg + 7) & ~7;
    if (lane < padded - deg)
      edge_s[w][deg + lane] = make_int2(0, 0);  // 0.0f bits, row 0 (L2-hot)
    __builtin_amdgcn_wave_barrier();
    // pass C: guard-free, 8 edges / iter, 2 wide gathers + 2 ds reads
    for (int j = 0; j < padded; j += 8) {
      const int2 e0 = edge_s[w][j + sub];
      const int2 e1 = edge_s[w][j + 4 + sub];
      const uint4 g0 = Whq[e0.y + fl];
      const uint4 g1 = Whq[e1.y + fl];
      fma8(acc, __int_as_float(e0.x), g0);
      fma8(acc, __int_as_float(e1.x), g1);
    }
  } else {
    // slow path (deg > 128, ~never at mean degree 16): 3-pass recompute,
    // keeps max-subtraction for safety.
    float m = -INFINITY;
    for (int idx = lane; idx < deg; idx += 64) {
      float v = f1i + f2[col[start + idx]];
      v = fmaxf(v, LRELU_ALPHA * v);
      m = fmaxf(m, v);
    }
#pragma unroll
    for (int o = 32; o > 0; o >>= 1) m = fmaxf(m, __shfl_xor(m, o));
    for (int idx = lane; idx < deg; idx += 64) {
      float v = f1i + f2[col[start + idx]];
      v = fmaxf(v, LRELU_ALPHA * v);
      s += __expf(v - m);
    }
#pragma unroll
    for (int o = 32; o > 0; o >>= 1) s += __shfl_xor(s, o);
    inv = 1.f / s;
    for (int j = 0; j < deg; j += 4) {
      const int e = j + sub;
      const bool ok = e < deg;
      const int c = ok ? col[start + e] : 0;
      float v = f1i + f2[c];
      v = fmaxf(v, LRELU_ALPHA * v);
      const float a = ok ? __expf(v - m) : 0.f;
      const uint4 g = Whq[c * 16 + fl];
      fma8(acc, a, g);
    }
  }

  // merge the 4 edge-subgroup partials (subs differ; fl groups independent)
#pragma unroll
  for (int i = 0; i < 8; ++i) {
    acc[i] += __shfl_xor(acc[i], 16);
    acc[i] += __shfl_xor(acc[i], 32);
  }
  if (sub < 2) {
    float4 r;
    r.x = elu1(((sub == 0) ? acc[0] : acc[4]) * inv);
    r.y = elu1(((sub == 0) ? acc[1] : acc[5]) * inv);
    r.z = elu1(((sub == 0) ? acc[2] : acc[6]) * inv);
    r.w = elu1(((sub == 0) ? acc[3] : acc[7]) * inv);
    *outp = r;
  }
}

// ---------------------------------------------------------------------------
extern "C" void kernel_launch(void* const* d_in, const int* in_sizes, int n_in,
                              void* d_out, int out_size, void* d_ws,
                              size_t ws_size, hipStream_t stream) {
  const float* h     = (const float*)d_in[0];
  const float* W     = (const float*)d_in[1];
  const float* a_src = (const float*)d_in[2];
  const float* a_dst = (const float*)d_in[3];
  const int*   row   = (const int*)d_in[4];
  const int*   col   = (const int*)d_in[5];
  float* out = (float*)d_out;

  char* ws = (char*)d_ws;
  unsigned short* Wh16 = (unsigned short*)(ws);        // N*128*2 = 25,600,000 B
  float* f1      = (float*)(ws + 25600000);            //    400,000 B
  float* f2      = (float*)(ws + 26000000);            //    400,000 B
  int*   row_ptr = (int*)  (ws + 26400000);            //    400,004 B
  unsigned short* Wt16 = (unsigned short*)(ws + 26800016);  // 64 KB, align16

  hipLaunchKernelGGL(prep_kernel, dim3(ROWPTR_BLOCKS + 128), dim3(256), 0,
                     stream, row, row_ptr, W, Wt16);
  hipLaunchKernelGGL(gemm_mfma, dim3((N_NODES + 63) / 64), dim3(256), 0,
                     stream, h, Wt16, a_src, a_dst, Wh16, f1, f2);
  hipLaunchKernelGGL(gat_v6, dim3(N_NODES / 4), dim3(256), 0, stream,
                     (const uint4*)Wh16, f1, f2, row_ptr, col, out);
}

// Round 5
// 254.720 us; speedup vs baseline: 1.1040x; 1.0113x over previous
//
#include <hip/hip_runtime.h>
#include <hip/hip_bf16.h>
#include <math.h>

#define N_NODES 100000
#define E_EDGES 1600000
#define IN_F 256
#define OUT_F 128
#define LRELU_ALPHA 0.2f

typedef __attribute__((ext_vector_type(8))) short bf16x8;
typedef __attribute__((ext_vector_type(4))) float f32x4;

__device__ __forceinline__ unsigned short f32_to_bf16(float f) {
  unsigned int u = __float_as_uint(f);
  u = (u + 0x7fffu + ((u >> 16) & 1u)) >> 16;  // round-to-nearest-even
  return (unsigned short)u;
}
// packed fp32x2 -> bf16x2 (low = a, high = b); uses v_cvt_pk_bf16_f32 on gfx950
__device__ __forceinline__ unsigned cvt2(float a, float b) {
  __hip_bfloat162 v = __float22bfloat162_rn(make_float2(a, b));
  unsigned u;
  __builtin_memcpy(&u, &v, 4);
  return u;
}
__device__ __forceinline__ float elu1(float x) {
  return x > 0.f ? x : __expf(x) - 1.f;
}

// fire-and-forget global -> LDS, 16 B per lane (dest = uniform base + lane*16)
typedef __attribute__((address_space(1))) const unsigned int gu32;
typedef __attribute__((address_space(3))) unsigned int lu32;
__device__ __forceinline__ void gll16(const void* g, void* l) {
  __builtin_amdgcn_global_load_lds((gu32*)g, (lu32*)l, 16, 0, 0);
}

// ---------------------------------------------------------------------------
// Prep: blocks [0,390]: row_ptr binary search; blocks [391,518]:
// Wt16[n][k] = bf16(W[k][n]).
// ---------------------------------------------------------------------------
#define ROWPTR_BLOCKS 391
__global__ void prep_kernel(const int* __restrict__ row,
                            int* __restrict__ row_ptr,
                            const float* __restrict__ W,
                            unsigned short* __restrict__ Wt16) {
  const int b = blockIdx.x;
  if (b < ROWPTR_BLOCKS) {
    const int i = b * 256 + threadIdx.x;
    if (i > N_NODES) return;
    int lo = 0, hi = E_EDGES;
    while (lo < hi) {
      const int mid = (lo + hi) >> 1;
      if (row[mid] < i) lo = mid + 1; else hi = mid;
    }
    row_ptr[i] = lo;
  } else {
    const int idx = (b - ROWPTR_BLOCKS) * 256 + threadIdx.x;  // 0..32767
    const int n = idx >> 8;
    const int k = idx & 255;
    Wt16[n * IN_F + k] = f32_to_bf16(W[k * OUT_F + n]);
  }
}

// ---------------------------------------------------------------------------
// Kernel 1: Wh16 = bf16(h @ W) via MFMA 16x16x32_bf16.  (unchanged from R4:
// 64x128 tile, 1563 blocks, global_load_lds width-16 staging, double-buffer,
// one barrier/iter, LDS 32 KB -> 5 blocks/CU.)
// ---------------------------------------------------------------------------
#define OS_STRIDE 136
__global__ __launch_bounds__(256) void gemm_mfma(
    const float* __restrict__ h, const unsigned short* __restrict__ Wt16,
    const float* __restrict__ a_src, const float* __restrict__ a_dst,
    unsigned short* __restrict__ Wh16, float* __restrict__ f1,
    float* __restrict__ f2) {
  __shared__ unsigned short lds_us[16384];  // 32768 B
  char* ldsb = (char*)lds_us;

  const int tid = threadIdx.x;
  const int lane = tid & 63;
  const int w = tid >> 6;        // wave 0..3
  const int wr = w >> 1;         // wave row 0..1 (x32 rows)
  const int wc = w & 1;          // wave col 0..1 (x64 cols)
  const int quad = lane >> 4;    // 0..3
  const int lm = lane & 15;      // m/n within tile
  const int m0 = blockIdx.x * 64;

  f32x4 acc[2][4];
#pragma unroll
  for (int a = 0; a < 2; ++a)
#pragma unroll
    for (int b = 0; b < 4; ++b) acc[a][b] = (f32x4){0.f, 0.f, 0.f, 0.f};

  auto stage = [&](int p, int k0) {
    char* Ab = ldsb + p * 16384;
    char* Bb = Ab + 8192;
#pragma unroll
    for (int i = 0; i < 2; ++i) {
      const int r = 8 * (w + 4 * i) + (lane >> 3);
      const int gr = min(m0 + r, N_NODES - 1);  // tail clamp
      const float* src = h + (size_t)gr * IN_F + k0 + ((lane & 7) << 2);
      gll16(src, Ab + (w + 4 * i) * 1024);
    }
#pragma unroll
    for (int i = 0; i < 2; ++i) {
      const int n = 16 * (w + 4 * i) + (lane >> 2);
      const unsigned short* src = Wt16 + n * IN_F + k0 + ((lane & 3) << 3);
      gll16(src, Bb + (w + 4 * i) * 1024);
    }
  };

  stage(0, 0);  // prologue
  int p = 0;
  for (int kt = 0; kt < 8; ++kt) {
    __syncthreads();  // drains this wave's glls for buf[p]; publishes buf[p]
    if (kt < 7) stage(p ^ 1, (kt + 1) * 32);  // fire-and-forget next tile

    const float* Af = (const float*)(ldsb + p * 16384);
    const unsigned short* Bf =
        (const unsigned short*)(ldsb + p * 16384 + 8192);
    bf16x8 af[2], bfr[4];
#pragma unroll
    for (int t = 0; t < 2; ++t) {
      const int r = wr * 32 + t * 16 + lm;
      const float4 u0 = *reinterpret_cast<const float4*>(Af + r * 32 + quad * 8);
      const float4 u1 =
          *reinterpret_cast<const float4*>(Af + r * 32 + quad * 8 + 4);
      uint4 pk;
      pk.x = cvt2(u0.x, u0.y); pk.y = cvt2(u0.z, u0.w);
      pk.z = cvt2(u1.x, u1.y); pk.w = cvt2(u1.z, u1.w);
      af[t] = *reinterpret_cast<bf16x8*>(&pk);
    }
#pragma unroll
    for (int tc = 0; tc < 4; ++tc) {
      const int n = wc * 64 + tc * 16 + lm;
      bfr[tc] = *reinterpret_cast<const bf16x8*>(Bf + n * 32 + quad * 8);
    }
#pragma unroll
    for (int tr = 0; tr < 2; ++tr)
#pragma unroll
      for (int tc = 0; tc < 4; ++tc)
        acc[tr][tc] = __builtin_amdgcn_mfma_f32_16x16x32_bf16(
            af[tr], bfr[tc], acc[tr][tc], 0, 0, 0);
    p ^= 1;
  }
  __syncthreads();  // all buf reads done; LDS free for epilogue reuse

  // ---- epilogue 1: f1/f2 partials (per-wave disjoint rows), no atomics
  float* fredp = (float*)(ldsb + 17408);  // [wc][64 rows][2] = 256 floats
  float asv[4], adv[4];
#pragma unroll
  for (int tc = 0; tc < 4; ++tc) {
    asv[tc] = a_src[wc * 64 + tc * 16 + lm];
    adv[tc] = a_dst[wc * 64 + tc * 16 + lm];
  }
#pragma unroll
  for (int tr = 0; tr < 2; ++tr) {
#pragma unroll
    for (int reg = 0; reg < 4; ++reg) {
      float p1 = 0.f, p2 = 0.f;
#pragma unroll
      for (int tc = 0; tc < 4; ++tc) {
        p1 = fmaf(acc[tr][tc][reg], asv[tc], p1);
        p2 = fmaf(acc[tr][tc][reg], adv[tc], p2);
      }
#pragma unroll
      for (int o = 1; o < 16; o <<= 1) {  // reduce the 16 lm lanes
        p1 += __shfl_xor(p1, o);
        p2 += __shfl_xor(p2, o);
      }
      if (lm == 0) {
        const int r = wr * 32 + tr * 16 + quad * 4 + reg;  // 0..63
        fredp[wc * 128 + r * 2 + 0] = p1;
        fredp[wc * 128 + r * 2 + 1] = p2;
      }
    }
  }

  // ---- epilogue 2: stage C tile (bf16) to LDS, combine f1/f2 halves
#pragma unroll
  for (int tr = 0; tr < 2; ++tr)
#pragma unroll
    for (int tc = 0; tc < 4; ++tc)
#pragma unroll
      for (int reg = 0; reg < 4; ++reg)
        lds_us[(wr * 32 + tr * 16 + quad * 4 + reg) * OS_STRIDE + wc * 64 +
               tc * 16 + lm] = f32_to_bf16(acc[tr][tc][reg]);
  __syncthreads();
  if (tid < 64 && m0 + tid < N_NODES) {
    f1[m0 + tid] = fredp[tid * 2 + 0] + fredp[128 + tid * 2 + 0];
    f2[m0 + tid] = fredp[tid * 2 + 1] + fredp[128 + tid * 2 + 1];
  }
  // copy-out: thread t -> row t/4 (0..63), quarter t&3 (64 B = 4 uint4)
  {
    const int rr = tid >> 2, part = tid & 3;
    if (m0 + rr < N_NODES) {
      uint4* dst =
          reinterpret_cast<uint4*>(&Wh16[(m0 + rr) * OUT_F + part * 32]);
      const uint4* src =
          reinterpret_cast<const uint4*>(&lds_us[rr * OS_STRIDE + part * 32]);
#pragma unroll
      for (int i = 0; i < 4; ++i) dst[i] = src[i];
    }
  }
}

// ---------------------------------------------------------------------------
// Kernel 2: segment softmax + SpMM + ELU. One wave per node, 4 nodes/block.
// v7: v5's lane-owns-2-features layout (1 dword gather per lane per edge,
// max MLP) with the edge pipeline deepened 8 -> 16: edge cache padded to a
// multiple of 16, inner loop guard-free with 16 independent ds_read_b64 +
// 16 independent dword gathers in flight per wave. For the mean node
// (deg 16) pass C is ONE iteration of 16 concurrent gathers (v6 had 4
// dependent rounds of 2 — measured regression; MLP depth wins here).
// ---------------------------------------------------------------------------
__global__ __launch_bounds__(256) void gat_v7(
    const unsigned int* __restrict__ Whu,  // Wh16 viewed as dwords [N][64]
    const float* __restrict__ f1, const float* __restrict__ f2,
    const int* __restrict__ row_ptr, const int* __restrict__ col,
    float* __restrict__ out) {
  __shared__ int2 edge_s[4][128];

  const int w = threadIdx.x >> 6;
  const int lane = threadIdx.x & 63;
  const int node = blockIdx.x * 4 + w;

  const int start = row_ptr[node];
  const int deg = row_ptr[node + 1] - start;
  float2* outp = reinterpret_cast<float2*>(&out[node * OUT_F + lane * 2]);

  if (deg == 0) {
    *outp = make_float2(0.f, 0.f);
    return;
  }
  const float f1i = f1[node];
  float acc0 = 0.f, acc1 = 0.f, s = 0.f, inv;

  if (deg <= 128) {
    // fused pass: logits -> exp -> LDS, running sum (no max subtraction:
    // logits are ~N(0,1.6^2), fp32-safe, exact-math identical to reference)
    for (int idx = lane; idx < deg; idx += 64) {
      const int c = col[start + idx];
      float v = f1i + f2[c];
      v = fmaxf(v, LRELU_ALPHA * v);  // leaky-relu, alpha < 1
      const float x = __expf(v);
      edge_s[w][idx] = make_int2(__float_as_int(x), c << 6);  // c*64 dword idx
      s += x;
    }
#pragma unroll
    for (int o = 32; o > 0; o >>= 1) s += __shfl_xor(s, o);
    inv = 1.f / s;
    __builtin_amdgcn_wave_barrier();
    // pad to multiple of 16 with zero-contribution entries (att=0, col=0)
    const int padded = (deg + 15) & ~15;
    if (lane < padded - deg)
      edge_s[w][deg + lane] = make_int2(0, 0);  // 0.0f bits, row 0 (L2-hot)
    __builtin_amdgcn_wave_barrier();
    // pass C: guard-free, 16 edges per iteration, 16 gathers in flight
    for (int j = 0; j < padded; j += 16) {
      int2 e[16];
#pragma unroll
      for (int u = 0; u < 16; ++u) e[u] = edge_s[w][j + u];
      unsigned g[16];
#pragma unroll
      for (int u = 0; u < 16; ++u) g[u] = Whu[e[u].y + lane];
#pragma unroll
      for (int u = 0; u < 16; ++u) {
        const float a = __int_as_float(e[u].x);
        acc0 = fmaf(a, __uint_as_float(g[u] << 16), acc0);
        acc1 = fmaf(a, __uint_as_float(g[u] & 0xffff0000u), acc1);
      }
    }
  } else {
    // slow path (deg > 128, ~never at mean degree 16): 3-pass recompute,
    // keeps max-subtraction for safety.
    float m = -INFINITY;
    for (int idx = lane; idx < deg; idx += 64) {
      float v = f1i + f2[col[start + idx]];
      v = fmaxf(v, LRELU_ALPHA * v);
      m = fmaxf(m, v);
    }
#pragma unroll
    for (int o = 32; o > 0; o >>= 1) m = fmaxf(m, __shfl_xor(m, o));
    for (int idx = lane; idx < deg; idx += 64) {
      float v = f1i + f2[col[start + idx]];
      v = fmaxf(v, LRELU_ALPHA * v);
      s += __expf(v - m);
    }
#pragma unroll
    for (int o = 32; o > 0; o >>= 1) s += __shfl_xor(s, o);
    inv = 1.f / s;
    for (int j = 0; j < deg; ++j) {
      const int c = col[start + j];
      float v = f1i + f2[c];
      v = fmaxf(v, LRELU_ALPHA * v);
      const float a = __expf(v - m);
      const unsigned g = Whu[c * 64 + lane];
      acc0 = fmaf(a, __uint_as_float(g << 16), acc0);
      acc1 = fmaf(a, __uint_as_float(g & 0xffff0000u), acc1);
    }
  }
  acc0 *= inv;
  acc1 *= inv;
  *outp = make_float2(elu1(acc0), elu1(acc1));
}

// ---------------------------------------------------------------------------
extern "C" void kernel_launch(void* const* d_in, const int* in_sizes, int n_in,
                              void* d_out, int out_size, void* d_ws,
                              size_t ws_size, hipStream_t stream) {
  const float* h     = (const float*)d_in[0];
  const float* W     = (const float*)d_in[1];
  const float* a_src = (const float*)d_in[2];
  const float* a_dst = (const float*)d_in[3];
  const int*   row   = (const int*)d_in[4];
  const int*   col   = (const int*)d_in[5];
  float* out = (float*)d_out;

  char* ws = (char*)d_ws;
  unsigned short* Wh16 = (unsigned short*)(ws);        // N*128*2 = 25,600,000 B
  float* f1      = (float*)(ws + 25600000);            //    400,000 B
  float* f2      = (float*)(ws + 26000000);            //    400,000 B
  int*   row_ptr = (int*)  (ws + 26400000);            //    400,004 B
  unsigned short* Wt16 = (unsigned short*)(ws + 26800016);  // 64 KB, align16

  hipLaunchKernelGGL(prep_kernel, dim3(ROWPTR_BLOCKS + 128), dim3(256), 0,
                     stream, row, row_ptr, W, Wt16);
  hipLaunchKernelGGL(gemm_mfma, dim3((N_NODES + 63) / 64), dim3(256), 0,
                     stream, h, Wt16, a_src, a_dst, Wh16, f1, f2);
  hipLaunchKernelGGL(gat_v7, dim3(N_NODES / 4), dim3(256), 0, stream,
                     (const unsigned int*)Wh16, f1, f2, row_ptr, col, out);
}